// Round 12
// baseline (776.600 us; speedup 1.0000x reference)
//
#include <hip/hip_runtime.h>
#include <hip/hip_bf16.h>

#define NN 50000
#define NE 600000
#define D 128
#define NL 5

typedef __hip_bfloat16 bf16;
typedef unsigned short ushort_t;
typedef _Float16 half_t;
typedef __attribute__((ext_vector_type(8))) _Float16 half8;
typedef __attribute__((ext_vector_type(4))) _Float16 half4;
typedef __attribute__((ext_vector_type(8))) short short8;
typedef __attribute__((ext_vector_type(4))) float f32x4;
typedef __attribute__((ext_vector_type(2))) float f32x2;

__device__ __forceinline__ float b2f(bf16 v) { return __bfloat162float(v); }

__device__ __forceinline__ float loadF(const void* p, long long i, int isf32) {
    if (isf32) return ((const float*)p)[i];
    return b2f(((const bf16*)p)[i]);
}

__global__ void detect_k(const void* __restrict__ atom, int* __restrict__ flag) {
    __shared__ int vote;
    if (threadIdx.x == 0) vote = 0;
    __syncthreads();
    unsigned short u = ((const unsigned short*)atom)[threadIdx.x];
    unsigned short ex = (u >> 7) & 0xFF;
    if (ex >= 0x90) atomicOr(&vote, 1);
    __syncthreads();
    if (threadIdx.x == 0) *flag = vote;
}

__global__ void zero_f(float* __restrict__ p, int n) {
    int i = blockIdx.x * 256 + threadIdx.x;
    if (i < n) p[i] = 0.f;
}
__global__ void zero_i(int* __restrict__ p, int n) {
    int i = blockIdx.x * 256 + threadIdx.x;
    if (i < n) p[i] = 0;
}

// convert + transpose weights to fp16 once per launch
__global__ void prepw_k(const void* __restrict__ W1, const void* __restrict__ W2,
                        const int* __restrict__ fl,
                        half_t* __restrict__ w1t, half_t* __restrict__ w2t) {
    int isf32 = *fl;
    int idx = blockIdx.x * 256 + threadIdx.x;
    const int per = NL * 2 * D * D;
    if (idx < per) {
        int l = idx / (2 * D * D);
        int r = idx % (2 * D * D);
        int n = r >> 7, k = r & 127;
        w1t[idx] = (half_t)loadF(W1, (long long)l * 2 * D * D + (long long)k * 256 + n, isf32);
    } else if (idx < 2 * per) {
        int j = idx - per;
        int l = j / (2 * D * D);
        int r = j % (2 * D * D);
        int n = r >> 8, k = r & 255;
        w2t[j] = (half_t)loadF(W2, (long long)l * 2 * D * D + (long long)k * D + n, isf32);
    }
}

// ---------------- CSR build ----------------
__global__ void hist_k(const int* __restrict__ ei, int* __restrict__ deg) {
    int e = blockIdx.x * 256 + threadIdx.x;
    if (e < NE) atomicAdd(&deg[ei[NE + e]], 1);
}

__global__ void scan1_k(const int* __restrict__ deg, int* __restrict__ tmp,
                        int* __restrict__ partial) {
    __shared__ int s[256];
    int t = threadIdx.x;
    int i = blockIdx.x * 256 + t;
    int v = (i < NN) ? deg[i] : 0;
    s[t] = v;
    __syncthreads();
    for (int off = 1; off < 256; off <<= 1) {
        int x = (t >= off) ? s[t - off] : 0;
        __syncthreads();
        s[t] += x;
        __syncthreads();
    }
    if (i < NN) tmp[i] = s[t];
    if (t == 255) partial[blockIdx.x] = s[255];
}

__global__ void scan2_k(int* __restrict__ partial, int nb) {
    __shared__ int s[256];
    int t = threadIdx.x;
    int v = (t < nb) ? partial[t] : 0;
    s[t] = v;
    __syncthreads();
    for (int off = 1; off < 256; off <<= 1) {
        int x = (t >= off) ? s[t - off] : 0;
        __syncthreads();
        s[t] += x;
        __syncthreads();
    }
    int excl = s[t] - v;
    __syncthreads();
    if (t < nb) partial[t] = excl;
}

__global__ void scan3_k(const int* __restrict__ tmp, const int* __restrict__ partial,
                        const int* __restrict__ deg,
                        int* __restrict__ row_start, int* __restrict__ next) {
    int i = blockIdx.x * 256 + threadIdx.x;
    if (i >= NN) return;
    int incl = tmp[i] + partial[i >> 8];
    row_start[i + 1] = incl;
    next[i] = incl - deg[i];
    if (i == 0) row_start[0] = 0;
}

__global__ void fill_k(const int* __restrict__ ei, const int* __restrict__ ea,
                       int* __restrict__ next, int* __restrict__ csr) {
    int e = blockIdx.x * 256 + threadIdx.x;
    if (e >= NE) return;
    int src = ei[e];
    int dst = ei[NE + e];
    int c = ea[2 * e] * 4 + ea[2 * e + 1];
    int pos = atomicAdd(&next[dst], 1);
    csr[pos] = src | (c << 16);
}

// ---------------- forward ----------------
// embedding -> fp16 hpost (layer-0 input; no BN on input)
__global__ void embed_k(const int* __restrict__ x,
                        const void* __restrict__ atom,
                        const void* __restrict__ chir,
                        const void* __restrict__ hyb,
                        const int* __restrict__ fl,
                        half_t* __restrict__ hpost) {
    int isf32 = *fl;
    int idx = blockIdx.x * 256 + threadIdx.x;   // over NN*64
    if (idx >= NN * 64) return;
    int n = idx >> 6, fp = (idx & 63) * 2;
    long long i0 = (long long)x[n * 3 + 0] * D + fp;
    long long i1 = (long long)x[n * 3 + 1] * D + fp;
    long long i2 = (long long)x[n * 3 + 2] * D + fp;
    float v0 = loadF(atom, i0, isf32) + loadF(chir, i1, isf32) + loadF(hyb, i2, isf32);
    float v1 = loadF(atom, i0 + 1, isf32) + loadF(chir, i1 + 1, isf32) + loadF(hyb, i2 + 1, isf32);
    half_t* dst = hpost + (long long)n * D + fp;
    dst[0] = (half_t)v0;
    dst[1] = (half_t)v1;
}

// per-node BN apply + ReLU: hpost = relu(scale*h2 + shift), fp16
__global__ void bnapply_k(const half_t* __restrict__ h2,
                          const float* __restrict__ norm,
                          half_t* __restrict__ hpost) {
    int idx = blockIdx.x * 256 + threadIdx.x;  // over NN*64
    if (idx >= NN * 64) return;
    int fp = (idx & 63) * 2;
    unsigned hv = *(const unsigned*)(h2 + (long long)(idx >> 6) * D + fp);
    float v0 = fmaf((float)((const half_t*)&hv)[0], norm[fp], norm[D + fp]);
    float v1 = fmaf((float)((const half_t*)&hv)[1], norm[fp + 1], norm[D + fp + 1]);
    v0 = fmaxf(v0, 0.f); v1 = fmaxf(v1, 0.f);
    half_t* dst = hpost + (long long)(idx >> 6) * D + fp;
    dst[0] = (half_t)v0;
    dst[1] = (half_t)v1;
}

// one wave per node, PURE gather (hpost already BN+ReLU'd); half-wave pairing.
// agg[n,:] (fp16) = sum_e (hpost[src,:] + comb[c,:])
__global__ __launch_bounds__(256) void aggr_k(
        const half_t* __restrict__ h,
        const int* __restrict__ row_start,
        const int* __restrict__ csr,
        const void* __restrict__ e1, const void* __restrict__ e2,
        const int* __restrict__ fl, int layer,
        half_t* __restrict__ agg) {
    __shared__ float comb[24 * D];
    int isf32 = *fl;
    long long e1off = (long long)layer * 6 * D;
    long long e2off = (long long)layer * 4 * D;
    for (int i = threadIdx.x; i < 24 * D; i += 256) {
        int c = i >> 7, f = i & 127;
        comb[i] = loadF(e1, e1off + (c >> 2) * D + f, isf32) +
                  loadF(e2, e2off + (c & 3) * D + f, isf32);
    }
    __syncthreads();
    int n = blockIdx.x * 4 + (threadIdx.x >> 6);
    int lane = threadIdx.x & 63;
    int hh = lane >> 5;              // half-wave id
    int f4 = (lane & 31) * 4;        // features f4..f4+3
    int beg = row_start[n], end = row_start[n + 1];
    float va[4] = {0.f, 0.f, 0.f, 0.f};
    float vb[4] = {0.f, 0.f, 0.f, 0.f};
    int i = beg;
    for (; i + 3 < end; i += 4) {
        int pkA = csr[i + hh];
        int pkB = csr[i + 2 + hh];
        unsigned long long gA = *(const unsigned long long*)(h + (long long)(pkA & 0xFFFF) * D + f4);
        unsigned long long gB = *(const unsigned long long*)(h + (long long)(pkB & 0xFFFF) * D + f4);
        f32x4 cA = *(const f32x4*)&comb[(pkA >> 16) * D + f4];
        f32x4 cB = *(const f32x4*)&comb[(pkB >> 16) * D + f4];
        const half_t* ga = (const half_t*)&gA;
        const half_t* gb = (const half_t*)&gB;
#pragma unroll
        for (int j = 0; j < 4; ++j) {
            va[j] += (float)ga[j] + cA[j];
            vb[j] += (float)gb[j] + cB[j];
        }
    }
    for (; i + 1 < end; i += 2) {
        int pk = csr[i + hh];
        unsigned long long g = *(const unsigned long long*)(h + (long long)(pk & 0xFFFF) * D + f4);
        f32x4 c = *(const f32x4*)&comb[(pk >> 16) * D + f4];
        const half_t* gh = (const half_t*)&g;
#pragma unroll
        for (int j = 0; j < 4; ++j) va[j] += (float)gh[j] + c[j];
    }
    if (i < end && hh == 0) {
        int pk = csr[i];
        unsigned long long g = *(const unsigned long long*)(h + (long long)(pk & 0xFFFF) * D + f4);
        f32x4 c = *(const f32x4*)&comb[(pk >> 16) * D + f4];
        const half_t* gh = (const half_t*)&g;
#pragma unroll
        for (int j = 0; j < 4; ++j) va[j] += (float)gh[j] + c[j];
    }
    half4 o;
#pragma unroll
    for (int j = 0; j < 4; ++j) {
        float v = va[j] + vb[j];
        v += __shfl_down(v, 32, 64);
        o[j] = (half_t)v;
    }
    if (hh == 0)
        *(half4*)(agg + (long long)n * D + f4) = o;
}

// Fused MLP: fp16 MFMA; A direct fp16 from agg; B1/B2 staged together in
// separate LDS arrays (3 syncs per nc). Writes raw pre-BN h2 fp16 + stats.
__global__ __launch_bounds__(256) void mlp_k(
        const half_t* __restrict__ agg,
        const half_t* __restrict__ w1t, const half_t* __restrict__ w2t,
        const void* __restrict__ b1, const void* __restrict__ b2,
        const int* __restrict__ fl, int layer,
        half_t* __restrict__ h2, float* __restrict__ stats) {
    __shared__ ushort_t Bs1[64 * 136];   // B1 chunk [n64][k128+pad]
    __shared__ ushort_t Bs2[128 * 72];   // B2 chunk [n128][k64+pad]
    __shared__ ushort_t Ms[64 * 72];     // mid chunk [m][k], fp16 bits
    __shared__ float SS[2 * D];
    int isf32 = *fl;
    int m0 = blockIdx.x * 64;
    long long b1off = (long long)layer * 2 * D;
    long long b2off = (long long)layer * D;
    int tid = threadIdx.x;
    int w = tid >> 6, lane = tid & 63;
    int quad = lane >> 4, l16 = lane & 15;
    SS[tid] = 0.f;

    int arow = m0 + w * 16 + l16;
    if (arow >= NN) arow = NN - 1;
    const half_t* ap = agg + (long long)arow * D + quad * 8;
    half8 afrag[4];
#pragma unroll
    for (int kk4 = 0; kk4 < 4; ++kk4)
        afrag[kk4] = *(const half8*)(ap + kk4 * 32);

    const half_t* w1p = w1t + (long long)layer * 256 * 128;
    const half_t* w2p = w2t + (long long)layer * 128 * 256;
    f32x4 acc[8];
#pragma unroll
    for (int t = 0; t < 8; ++t) acc[t] = (f32x4){0.f, 0.f, 0.f, 0.f};

    for (int nc = 0; nc < 4; ++nc) {
        __syncthreads();  // prev gemm2's Bs2/Ms reads done (and SS init at nc=0)
        {   // stage B1 chunk (rows nc*64..+64 of w1t, 128 k each)
            int r = tid >> 2, kq = (tid & 3) * 32;
            const ushort_t* src = (const ushort_t*)(w1p + (long long)(nc * 64 + r) * 128 + kq);
            ushort_t* dst = &Bs1[r * 136 + kq];
#pragma unroll
            for (int t = 0; t < 4; ++t)
                *(short8*)(dst + t * 8) = *(const short8*)(src + t * 8);
        }
        {   // stage B2 chunk (all 128 n-rows, k-cols nc*64..+64 of w2t)
            int r = tid >> 1, kq = (tid & 1) * 32;
            const ushort_t* src = (const ushort_t*)(w2p + (long long)r * 256 + nc * 64 + kq);
            ushort_t* dst = &Bs2[r * 72 + kq];
#pragma unroll
            for (int t = 0; t < 4; ++t)
                *(short8*)(dst + t * 8) = *(const short8*)(src + t * 8);
        }
        __syncthreads();  // B1,B2 staged
        f32x4 macc[4];
#pragma unroll
        for (int nt = 0; nt < 4; ++nt) macc[nt] = (f32x4){0.f, 0.f, 0.f, 0.f};
#pragma unroll
        for (int kk4 = 0; kk4 < 4; ++kk4) {
            half8 a = afrag[kk4];
#pragma unroll
            for (int nt = 0; nt < 4; ++nt) {
                half8 b = *(const half8*)&Bs1[(nt * 16 + l16) * 136 + kk4 * 32 + quad * 8];
                macc[nt] = __builtin_amdgcn_mfma_f32_16x16x32_f16(a, b, macc[nt], 0, 0, 0);
            }
        }
        // bias + relu -> Ms (prev gemm2 Ms reads guarded by top sync)
#pragma unroll
        for (int nt = 0; nt < 4; ++nt) {
            float bias = loadF(b1, b1off + nc * 64 + nt * 16 + l16, isf32);
#pragma unroll
            for (int r = 0; r < 4; ++r) {
                float v = fmaxf(macc[nt][r] + bias, 0.f);
                half_t hv = (half_t)v;
                Ms[(w * 16 + quad * 4 + r) * 72 + nt * 16 + l16] = *(ushort_t*)&hv;
            }
        }
        __syncthreads();  // Ms visible
#pragma unroll
        for (int kk4 = 0; kk4 < 2; ++kk4) {
            half8 a = *(const half8*)&Ms[(w * 16 + l16) * 72 + kk4 * 32 + quad * 8];
#pragma unroll
            for (int t = 0; t < 8; ++t) {
                half8 b = *(const half8*)&Bs2[((t >> 2) * 64 + (t & 3) * 16 + l16) * 72 + kk4 * 32 + quad * 8];
                acc[t] = __builtin_amdgcn_mfma_f32_16x16x32_f16(a, b, acc[t], 0, 0, 0);
            }
        }
    }
#pragma unroll
    for (int t = 0; t < 8; ++t) {
        int col = (t >> 2) * 64 + (t & 3) * 16 + l16;
        float bias = loadF(b2, b2off + col, isf32);
        float s = 0.f, q = 0.f;
#pragma unroll
        for (int r = 0; r < 4; ++r) {
            int row = m0 + w * 16 + quad * 4 + r;
            if (row < NN) {
                float v = acc[t][r] + bias;
                h2[(long long)row * D + col] = (half_t)v;
                s += v; q += v * v;
            }
        }
        atomicAdd(&SS[col], s);
        atomicAdd(&SS[D + col], q);
    }
    __syncthreads();
    atomicAdd(&stats[tid], SS[tid]);
}

__global__ void finalize_k(float* __restrict__ stats,
                           const void* __restrict__ gamma,
                           const void* __restrict__ beta,
                           const int* __restrict__ fl, int layer,
                           float* __restrict__ norm) {
    int isf32 = *fl;
    int t = threadIdx.x;
    if (t < D) {
        float mu = stats[t] * (1.f / NN);
        float var = fmaxf(stats[D + t] * (1.f / NN) - mu * mu, 0.f);
        float rs = rsqrtf(var + 1e-5f);
        float sc = rs * loadF(gamma, (long long)layer * D + t, isf32);
        float sh = loadF(beta, (long long)layer * D + t, isf32) - mu * sc;
        norm[t] = sc;
        norm[D + t] = sh;
    }
    stats[t] = 0.f;
}

// final output: out = scale*h2 + shift (f32, no relu)
__global__ void apply_k(const half_t* __restrict__ h2,
                        const float* __restrict__ norm,
                        float* __restrict__ out) {
    int idx = blockIdx.x * 256 + threadIdx.x;  // over NN*64
    if (idx >= NN * 64) return;
    int fp = (idx & 63) * 2;
    unsigned hv = *(const unsigned*)(h2 + (long long)(idx >> 6) * D + fp);
    float v0 = fmaf((float)((const half_t*)&hv)[0], norm[fp], norm[D + fp]);
    float v1 = fmaf((float)((const half_t*)&hv)[1], norm[fp + 1], norm[D + fp + 1]);
    f32x2 o; o.x = v0; o.y = v1;
    *(f32x2*)(out + (long long)(idx >> 6) * D + fp) = o;
}

extern "C" void kernel_launch(void* const* d_in, const int* in_sizes, int n_in,
                              void* d_out, int out_size, void* d_ws, size_t ws_size,
                              hipStream_t stream) {
    const int* x     = (const int*)d_in[0];
    const int* ei    = (const int*)d_in[1];
    const int* ea    = (const int*)d_in[2];
    const void* atom = d_in[3];
    const void* chir = d_in[4];
    const void* hyb  = d_in[5];
    const void* e1   = d_in[6];
    const void* e2   = d_in[7];
    const void* W1   = d_in[8];
    const void* b1   = d_in[9];
    const void* W2   = d_in[10];
    const void* b2   = d_in[11];
    const void* gm   = d_in[12];
    const void* bt   = d_in[13];

    const size_t ND = (size_t)NN * D;

    char* base = (char*)d_ws;
    float* stats   = (float*)base;
    float* norm    = (float*)(base + 1024);
    int*   flag    = (int*)(base + 2048);
    char*  p       = base + 4096;
    half_t* hpost  = (half_t*)p;  p += ND * 2;
    half_t* h2     = (half_t*)p;  p += ND * 2;
    half_t* w1t    = (half_t*)p;  p += (size_t)NL * 2 * D * D * 2;
    half_t* w2t    = (half_t*)p;  p += (size_t)NL * 2 * D * D * 2;
    int* csr       = (int*)p;     p += (size_t)NE * 4;
    int* row_start = (int*)p;     p += (size_t)(NN + 1) * 4 + 12;
    int* deg       = (int*)p;     p += (size_t)NN * 4;
    int* tmp       = (int*)p;     p += (size_t)NN * 4;
    int* next      = (int*)p;     p += (size_t)NN * 4;
    int* partial   = (int*)p;

    half_t* aggf = (half_t*)d_out;  // fp16 agg scratch (12.8MB of the 25.6MB
                                    // f32 out buffer); dead before apply_k

    const int N2_BLOCKS = (NN * 64 + 255) / 256;  // 12500
    const int E_BLOCKS  = (NE + 255) / 256;       // 2344
    const int N_BLOCKS  = (NN + 255) / 256;       // 196
    const int M_TILES   = (NN + 63) / 64;         // 782
    const int PW_BLOCKS = (2 * NL * 2 * D * D + 255) / 256;  // 1280

    detect_k<<<1, 256, 0, stream>>>(atom, flag);
    prepw_k<<<PW_BLOCKS, 256, 0, stream>>>(W1, W2, flag, w1t, w2t);

    zero_i<<<N_BLOCKS, 256, 0, stream>>>(deg, NN);
    hist_k<<<E_BLOCKS, 256, 0, stream>>>(ei, deg);
    scan1_k<<<N_BLOCKS, 256, 0, stream>>>(deg, tmp, partial);
    scan2_k<<<1, 256, 0, stream>>>(partial, N_BLOCKS);
    scan3_k<<<N_BLOCKS, 256, 0, stream>>>(tmp, partial, deg, row_start, next);
    fill_k<<<E_BLOCKS, 256, 0, stream>>>(ei, ea, next, csr);

    embed_k<<<N2_BLOCKS, 256, 0, stream>>>(x, atom, chir, hyb, flag, hpost);
    zero_f<<<1, 256, 0, stream>>>(stats, 2 * D);

    for (int l = 0; l < NL; ++l) {
        if (l > 0)
            bnapply_k<<<N2_BLOCKS, 256, 0, stream>>>(h2, norm, hpost);
        aggr_k<<<NN / 4, 256, 0, stream>>>(hpost, row_start, csr,
                                           e1, e2, flag, l, aggf);
        mlp_k<<<M_TILES, 256, 0, stream>>>(aggf, w1t, w2t, b1, b2, flag, l, h2, stats);
        finalize_k<<<1, 256, 0, stream>>>(stats, gm, bt, flag, l, norm);
    }
    apply_k<<<N2_BLOCKS, 256, 0, stream>>>(h2, norm, (float*)d_out);
}

// Round 13
// 702.596 us; speedup vs baseline: 1.1053x; 1.1053x over previous
//
#include <hip/hip_runtime.h>
#include <hip/hip_bf16.h>

#define NN 50000
#define NE 600000
#define D 128
#define NL 5

typedef __hip_bfloat16 bf16;
typedef unsigned short ushort_t;
typedef _Float16 half_t;
typedef __attribute__((ext_vector_type(8))) _Float16 half8;
typedef __attribute__((ext_vector_type(4))) _Float16 half4;
typedef __attribute__((ext_vector_type(8))) short short8;
typedef __attribute__((ext_vector_type(4))) float f32x4;
typedef __attribute__((ext_vector_type(2))) float f32x2;

__device__ __forceinline__ float b2f(bf16 v) { return __bfloat162float(v); }

__device__ __forceinline__ float loadF(const void* p, long long i, int isf32) {
    if (isf32) return ((const float*)p)[i];
    return b2f(((const bf16*)p)[i]);
}

__global__ void detect_k(const void* __restrict__ atom, int* __restrict__ flag) {
    __shared__ int vote;
    if (threadIdx.x == 0) vote = 0;
    __syncthreads();
    unsigned short u = ((const unsigned short*)atom)[threadIdx.x];
    unsigned short ex = (u >> 7) & 0xFF;
    if (ex >= 0x90) atomicOr(&vote, 1);
    __syncthreads();
    if (threadIdx.x == 0) *flag = vote;
}

__global__ void zero_f(float* __restrict__ p, int n) {
    int i = blockIdx.x * 256 + threadIdx.x;
    if (i < n) p[i] = 0.f;
}
__global__ void zero_i(int* __restrict__ p, int n) {
    int i = blockIdx.x * 256 + threadIdx.x;
    if (i < n) p[i] = 0;
}

// convert + transpose weights to fp16 once per launch
__global__ void prepw_k(const void* __restrict__ W1, const void* __restrict__ W2,
                        const int* __restrict__ fl,
                        half_t* __restrict__ w1t, half_t* __restrict__ w2t) {
    int isf32 = *fl;
    int idx = blockIdx.x * 256 + threadIdx.x;
    const int per = NL * 2 * D * D;
    if (idx < per) {
        int l = idx / (2 * D * D);
        int r = idx % (2 * D * D);
        int n = r >> 7, k = r & 127;
        w1t[idx] = (half_t)loadF(W1, (long long)l * 2 * D * D + (long long)k * 256 + n, isf32);
    } else if (idx < 2 * per) {
        int j = idx - per;
        int l = j / (2 * D * D);
        int r = j % (2 * D * D);
        int n = r >> 8, k = r & 255;
        w2t[j] = (half_t)loadF(W2, (long long)l * 2 * D * D + (long long)k * D + n, isf32);
    }
}

// ---------------- CSR build ----------------
__global__ void hist_k(const int* __restrict__ ei, int* __restrict__ deg) {
    int e = blockIdx.x * 256 + threadIdx.x;
    if (e < NE) atomicAdd(&deg[ei[NE + e]], 1);
}

__global__ void scan1_k(const int* __restrict__ deg, int* __restrict__ tmp,
                        int* __restrict__ partial) {
    __shared__ int s[256];
    int t = threadIdx.x;
    int i = blockIdx.x * 256 + t;
    int v = (i < NN) ? deg[i] : 0;
    s[t] = v;
    __syncthreads();
    for (int off = 1; off < 256; off <<= 1) {
        int x = (t >= off) ? s[t - off] : 0;
        __syncthreads();
        s[t] += x;
        __syncthreads();
    }
    if (i < NN) tmp[i] = s[t];
    if (t == 255) partial[blockIdx.x] = s[255];
}

__global__ void scan2_k(int* __restrict__ partial, int nb) {
    __shared__ int s[256];
    int t = threadIdx.x;
    int v = (t < nb) ? partial[t] : 0;
    s[t] = v;
    __syncthreads();
    for (int off = 1; off < 256; off <<= 1) {
        int x = (t >= off) ? s[t - off] : 0;
        __syncthreads();
        s[t] += x;
        __syncthreads();
    }
    int excl = s[t] - v;
    __syncthreads();
    if (t < nb) partial[t] = excl;
}

__global__ void scan3_k(const int* __restrict__ tmp, const int* __restrict__ partial,
                        const int* __restrict__ deg,
                        int* __restrict__ row_start, int* __restrict__ next) {
    int i = blockIdx.x * 256 + threadIdx.x;
    if (i >= NN) return;
    int incl = tmp[i] + partial[i >> 8];
    row_start[i + 1] = incl;
    next[i] = incl - deg[i];
    if (i == 0) row_start[0] = 0;
}

__global__ void fill_k(const int* __restrict__ ei, const int* __restrict__ ea,
                       int* __restrict__ next, int* __restrict__ csr) {
    int e = blockIdx.x * 256 + threadIdx.x;
    if (e >= NE) return;
    int src = ei[e];
    int dst = ei[NE + e];
    int c = ea[2 * e] * 4 + ea[2 * e + 1];
    int pos = atomicAdd(&next[dst], 1);
    csr[pos] = src | (c << 16);
}

// ---------------- forward ----------------
// embedding -> raw fp16 h2 (layer-0 aggr uses identity norm, no relu)
__global__ void embed_k(const int* __restrict__ x,
                        const void* __restrict__ atom,
                        const void* __restrict__ chir,
                        const void* __restrict__ hyb,
                        const int* __restrict__ fl,
                        half_t* __restrict__ h2) {
    int isf32 = *fl;
    int idx = blockIdx.x * 256 + threadIdx.x;   // over NN*64
    if (idx >= NN * 64) return;
    int n = idx >> 6, fp = (idx & 63) * 2;
    long long i0 = (long long)x[n * 3 + 0] * D + fp;
    long long i1 = (long long)x[n * 3 + 1] * D + fp;
    long long i2 = (long long)x[n * 3 + 2] * D + fp;
    float v0 = loadF(atom, i0, isf32) + loadF(chir, i1, isf32) + loadF(hyb, i2, isf32);
    float v1 = loadF(atom, i0 + 1, isf32) + loadF(chir, i1 + 1, isf32) + loadF(hyb, i2 + 1, isf32);
    half_t* dst = h2 + (long long)n * D + fp;
    dst[0] = (half_t)v0;
    dst[1] = (half_t)v1;
}

// one wave per node; half-wave edge-pairing; BN(prev layer)+ReLU applied
// per gathered element. norm computed inline from statsPrev (gamma/beta of
// layer-1). agg[n,:] (fp16) = sum_e (BNrelu(h2[src,:]) + comb[c,:])
__global__ __launch_bounds__(256) void aggr_k(
        const half_t* __restrict__ h,
        const float* __restrict__ statsPrev,
        const int* __restrict__ row_start,
        const int* __restrict__ csr,
        const void* __restrict__ e1, const void* __restrict__ e2,
        const void* __restrict__ gm, const void* __restrict__ bt,
        const int* __restrict__ fl, int layer,
        half_t* __restrict__ agg) {
    __shared__ float comb[24 * D];
    __shared__ float norm_s[2 * D];
    int isf32 = *fl;
    int tid = threadIdx.x;
    long long e1off = (long long)layer * 6 * D;
    long long e2off = (long long)layer * 4 * D;
    for (int i = tid; i < 24 * D; i += 256) {
        int c = i >> 7, f = i & 127;
        comb[i] = loadF(e1, e1off + (c >> 2) * D + f, isf32) +
                  loadF(e2, e2off + (c & 3) * D + f, isf32);
    }
    if (tid < D) {
        float sc, sh;
        if (layer == 0) { sc = 1.f; sh = 0.f; }
        else {
            float mu = statsPrev[tid] * (1.f / NN);
            float var = fmaxf(statsPrev[D + tid] * (1.f / NN) - mu * mu, 0.f);
            float rs = rsqrtf(var + 1e-5f);
            sc = rs * loadF(gm, (long long)(layer - 1) * D + tid, isf32);
            sh = loadF(bt, (long long)(layer - 1) * D + tid, isf32) - mu * sc;
        }
        norm_s[tid] = sc;
        norm_s[D + tid] = sh;
    }
    __syncthreads();
    int n = blockIdx.x * 4 + (tid >> 6);
    int lane = tid & 63;
    int hh = lane >> 5;              // half-wave id
    int f4 = (lane & 31) * 4;        // features f4..f4+3
    f32x4 sc4 = *(const f32x4*)&norm_s[f4];
    f32x4 sh4 = *(const f32x4*)&norm_s[D + f4];
    int relu = (layer > 0);
    int beg = row_start[n], end = row_start[n + 1];
    float va[4] = {0.f, 0.f, 0.f, 0.f};
    float vb[4] = {0.f, 0.f, 0.f, 0.f};
    int i = beg;
    for (; i + 3 < end; i += 4) {
        int pkA = csr[i + hh];
        int pkB = csr[i + 2 + hh];
        unsigned long long gA = *(const unsigned long long*)(h + (long long)(pkA & 0xFFFF) * D + f4);
        unsigned long long gB = *(const unsigned long long*)(h + (long long)(pkB & 0xFFFF) * D + f4);
        f32x4 cA = *(const f32x4*)&comb[(pkA >> 16) * D + f4];
        f32x4 cB = *(const f32x4*)&comb[(pkB >> 16) * D + f4];
        const half_t* ga = (const half_t*)&gA;
        const half_t* gb = (const half_t*)&gB;
#pragma unroll
        for (int j = 0; j < 4; ++j) {
            float a = fmaf((float)ga[j], sc4[j], sh4[j]);
            float b = fmaf((float)gb[j], sc4[j], sh4[j]);
            if (relu) { a = fmaxf(a, 0.f); b = fmaxf(b, 0.f); }
            va[j] += a + cA[j];
            vb[j] += b + cB[j];
        }
    }
    for (; i + 1 < end; i += 2) {
        int pk = csr[i + hh];
        unsigned long long g = *(const unsigned long long*)(h + (long long)(pk & 0xFFFF) * D + f4);
        f32x4 c = *(const f32x4*)&comb[(pk >> 16) * D + f4];
        const half_t* gh = (const half_t*)&g;
#pragma unroll
        for (int j = 0; j < 4; ++j) {
            float a = fmaf((float)gh[j], sc4[j], sh4[j]);
            if (relu) a = fmaxf(a, 0.f);
            va[j] += a + c[j];
        }
    }
    if (i < end && hh == 0) {
        int pk = csr[i];
        unsigned long long g = *(const unsigned long long*)(h + (long long)(pk & 0xFFFF) * D + f4);
        f32x4 c = *(const f32x4*)&comb[(pk >> 16) * D + f4];
        const half_t* gh = (const half_t*)&g;
#pragma unroll
        for (int j = 0; j < 4; ++j) {
            float a = fmaf((float)gh[j], sc4[j], sh4[j]);
            if (relu) a = fmaxf(a, 0.f);
            va[j] += a + c[j];
        }
    }
    half4 o;
#pragma unroll
    for (int j = 0; j < 4; ++j) {
        float v = va[j] + vb[j];
        v += __shfl_down(v, 32, 64);
        o[j] = (half_t)v;
    }
    if (hh == 0)
        *(half4*)(agg + (long long)n * D + f4) = o;
}

// Fused MLP: 512 threads, 128-row M-tile (8 waves x 16 rows). fp16 MFMA,
// B1/B2 chunks staged in LDS (same bytes serve 2x MFMA vs 64-row tile).
// Writes raw pre-BN h2 fp16 + per-feature stats (ping-pong); block 0 zeros
// the dead stats buffer for the next layer.
__global__ __launch_bounds__(512) void mlp_k(
        const half_t* __restrict__ agg,
        const half_t* __restrict__ w1t, const half_t* __restrict__ w2t,
        const void* __restrict__ b1, const void* __restrict__ b2,
        const int* __restrict__ fl, int layer,
        half_t* __restrict__ h2,
        float* __restrict__ statsAdd, float* __restrict__ statsZero) {
    __shared__ ushort_t Bs1[64 * 136];   // B1 chunk [n64][k128+pad]
    __shared__ ushort_t Bs2[128 * 72];   // B2 chunk [n128][k64+pad]
    __shared__ ushort_t Ms[128 * 72];    // mid chunk [m128][k64+pad]
    __shared__ float SS[2 * D];
    int isf32 = *fl;
    int m0 = blockIdx.x * 128;
    long long b1off = (long long)layer * 2 * D;
    long long b2off = (long long)layer * D;
    int tid = threadIdx.x;
    if (blockIdx.x == 0 && tid < 2 * D) statsZero[tid] = 0.f;
    if (tid < 2 * D) SS[tid] = 0.f;
    int w = tid >> 6, lane = tid & 63;
    int quad = lane >> 4, l16 = lane & 15;

    int arow = m0 + w * 16 + l16;
    if (arow >= NN) arow = NN - 1;
    const half_t* ap = agg + (long long)arow * D + quad * 8;
    half8 afrag[4];
#pragma unroll
    for (int kk4 = 0; kk4 < 4; ++kk4)
        afrag[kk4] = *(const half8*)(ap + kk4 * 32);

    const half_t* w1p = w1t + (long long)layer * 256 * 128;
    const half_t* w2p = w2t + (long long)layer * 128 * 256;
    f32x4 acc[8];
#pragma unroll
    for (int t = 0; t < 8; ++t) acc[t] = (f32x4){0.f, 0.f, 0.f, 0.f};

    for (int nc = 0; nc < 4; ++nc) {
        __syncthreads();  // prev gemm2's Bs2/Ms reads done; SS init (nc=0)
        {   // stage B1 chunk: 64 rows x 128 ushorts, 512 thr -> 16 ushorts each
            int r = tid >> 3, kq = (tid & 7) * 16;
            const ushort_t* src = (const ushort_t*)(w1p + (long long)(nc * 64 + r) * 128 + kq);
            ushort_t* dst = &Bs1[r * 136 + kq];
            *(short8*)(dst) = *(const short8*)(src);
            *(short8*)(dst + 8) = *(const short8*)(src + 8);
        }
        {   // stage B2 chunk: 128 rows x 64 ushorts
            int r = tid >> 2, kq = (tid & 3) * 16;
            const ushort_t* src = (const ushort_t*)(w2p + (long long)r * 256 + nc * 64 + kq);
            ushort_t* dst = &Bs2[r * 72 + kq];
            *(short8*)(dst) = *(const short8*)(src);
            *(short8*)(dst + 8) = *(const short8*)(src + 8);
        }
        __syncthreads();  // B1,B2 staged
        f32x4 macc[4];
#pragma unroll
        for (int nt = 0; nt < 4; ++nt) macc[nt] = (f32x4){0.f, 0.f, 0.f, 0.f};
#pragma unroll
        for (int kk4 = 0; kk4 < 4; ++kk4) {
            half8 a = afrag[kk4];
#pragma unroll
            for (int nt = 0; nt < 4; ++nt) {
                half8 b = *(const half8*)&Bs1[(nt * 16 + l16) * 136 + kk4 * 32 + quad * 8];
                macc[nt] = __builtin_amdgcn_mfma_f32_16x16x32_f16(a, b, macc[nt], 0, 0, 0);
            }
        }
        // bias + relu -> Ms (C-layout -> A-layout via LDS)
#pragma unroll
        for (int nt = 0; nt < 4; ++nt) {
            float bias = loadF(b1, b1off + nc * 64 + nt * 16 + l16, isf32);
#pragma unroll
            for (int r = 0; r < 4; ++r) {
                float v = fmaxf(macc[nt][r] + bias, 0.f);
                half_t hv = (half_t)v;
                Ms[(w * 16 + quad * 4 + r) * 72 + nt * 16 + l16] = *(ushort_t*)&hv;
            }
        }
        __syncthreads();  // Ms visible
#pragma unroll
        for (int kk4 = 0; kk4 < 2; ++kk4) {
            half8 a = *(const half8*)&Ms[(w * 16 + l16) * 72 + kk4 * 32 + quad * 8];
#pragma unroll
            for (int t = 0; t < 8; ++t) {
                half8 b = *(const half8*)&Bs2[((t >> 2) * 64 + (t & 3) * 16 + l16) * 72 + kk4 * 32 + quad * 8];
                acc[t] = __builtin_amdgcn_mfma_f32_16x16x32_f16(a, b, acc[t], 0, 0, 0);
            }
        }
    }
#pragma unroll
    for (int t = 0; t < 8; ++t) {
        int col = (t >> 2) * 64 + (t & 3) * 16 + l16;
        float bias = loadF(b2, b2off + col, isf32);
        float s = 0.f, q = 0.f;
#pragma unroll
        for (int r = 0; r < 4; ++r) {
            int row = m0 + w * 16 + quad * 4 + r;
            if (row < NN) {
                float v = acc[t][r] + bias;
                h2[(long long)row * D + col] = (half_t)v;
                s += v; q += v * v;
            }
        }
        atomicAdd(&SS[col], s);
        atomicAdd(&SS[D + col], q);
    }
    __syncthreads();
    if (tid < 2 * D) atomicAdd(&statsAdd[tid], SS[tid]);
}

// final output: out = BN(h2) with gamma/beta of last layer (no relu), f32
__global__ void apply_k(const half_t* __restrict__ h2,
                        const float* __restrict__ statsPrev,
                        const void* __restrict__ gm, const void* __restrict__ bt,
                        const int* __restrict__ fl,
                        float* __restrict__ out) {
    __shared__ float norm_s[2 * D];
    int isf32 = *fl;
    int tid = threadIdx.x;
    if (tid < D) {
        float mu = statsPrev[tid] * (1.f / NN);
        float var = fmaxf(statsPrev[D + tid] * (1.f / NN) - mu * mu, 0.f);
        float rs = rsqrtf(var + 1e-5f);
        float sc = rs * loadF(gm, (long long)(NL - 1) * D + tid, isf32);
        float sh = loadF(bt, (long long)(NL - 1) * D + tid, isf32) - mu * sc;
        norm_s[tid] = sc;
        norm_s[D + tid] = sh;
    }
    __syncthreads();
    int idx = blockIdx.x * 256 + tid;  // over NN*64
    if (idx >= NN * 64) return;
    int fp = (idx & 63) * 2;
    unsigned hv = *(const unsigned*)(h2 + (long long)(idx >> 6) * D + fp);
    float v0 = fmaf((float)((const half_t*)&hv)[0], norm_s[fp], norm_s[D + fp]);
    float v1 = fmaf((float)((const half_t*)&hv)[1], norm_s[fp + 1], norm_s[D + fp + 1]);
    f32x2 o; o.x = v0; o.y = v1;
    *(f32x2*)(out + (long long)(idx >> 6) * D + fp) = o;
}

extern "C" void kernel_launch(void* const* d_in, const int* in_sizes, int n_in,
                              void* d_out, int out_size, void* d_ws, size_t ws_size,
                              hipStream_t stream) {
    const int* x     = (const int*)d_in[0];
    const int* ei    = (const int*)d_in[1];
    const int* ea    = (const int*)d_in[2];
    const void* atom = d_in[3];
    const void* chir = d_in[4];
    const void* hyb  = d_in[5];
    const void* e1   = d_in[6];
    const void* e2   = d_in[7];
    const void* W1   = d_in[8];
    const void* b1   = d_in[9];
    const void* W2   = d_in[10];
    const void* b2   = d_in[11];
    const void* gm   = d_in[12];
    const void* bt   = d_in[13];

    const size_t ND = (size_t)NN * D;

    char* base = (char*)d_ws;
    float* SP0     = (float*)base;            // stats buffer 0 (256 f32)
    float* SP1     = (float*)(base + 1024);   // stats buffer 1
    int*   flag    = (int*)(base + 2048);
    char*  p       = base + 4096;
    half_t* h2     = (half_t*)p;  p += ND * 2;
    half_t* w1t    = (half_t*)p;  p += (size_t)NL * 2 * D * D * 2;
    half_t* w2t    = (half_t*)p;  p += (size_t)NL * 2 * D * D * 2;
    int* csr       = (int*)p;     p += (size_t)NE * 4;
    int* row_start = (int*)p;     p += (size_t)(NN + 1) * 4 + 12;
    int* deg       = (int*)p;     p += (size_t)NN * 4;
    int* tmp       = (int*)p;     p += (size_t)NN * 4;
    int* next      = (int*)p;     p += (size_t)NN * 4;
    int* partial   = (int*)p;

    half_t* aggf = (half_t*)d_out;  // fp16 agg scratch; dead before apply_k

    const int N2_BLOCKS = (NN * 64 + 255) / 256;  // 12500
    const int E_BLOCKS  = (NE + 255) / 256;       // 2344
    const int N_BLOCKS  = (NN + 255) / 256;       // 196
    const int M_TILES   = (NN + 127) / 128;       // 391
    const int PW_BLOCKS = (2 * NL * 2 * D * D + 255) / 256;  // 1280

    detect_k<<<1, 256, 0, stream>>>(atom, flag);
    prepw_k<<<PW_BLOCKS, 256, 0, stream>>>(W1, W2, flag, w1t, w2t);

    zero_i<<<N_BLOCKS, 256, 0, stream>>>(deg, NN);
    hist_k<<<E_BLOCKS, 256, 0, stream>>>(ei, deg);
    scan1_k<<<N_BLOCKS, 256, 0, stream>>>(deg, tmp, partial);
    scan2_k<<<1, 256, 0, stream>>>(partial, N_BLOCKS);
    scan3_k<<<N_BLOCKS, 256, 0, stream>>>(tmp, partial, deg, row_start, next);
    fill_k<<<E_BLOCKS, 256, 0, stream>>>(ei, ea, next, csr);

    embed_k<<<N2_BLOCKS, 256, 0, stream>>>(x, atom, chir, hyb, flag, h2);
    zero_f<<<2, 256, 0, stream>>>(SP0, 2 * 2 * D);  // zero both stats buffers

    for (int l = 0; l < NL; ++l) {
        float* sPrev = ((l - 1) & 1) ? SP1 : SP0;   // stats of layer l-1 (l>0)
        float* sAdd  = (l & 1) ? SP1 : SP0;
        float* sZero = ((l + 1) & 1) ? SP1 : SP0;
        aggr_k<<<NN / 4, 256, 0, stream>>>(h2, sPrev, row_start, csr,
                                           e1, e2, gm, bt, flag, l, aggf);
        mlp_k<<<M_TILES, 512, 0, stream>>>(aggf, w1t, w2t, b1, b2, flag, l,
                                           h2, sAdd, sZero);
    }
    apply_k<<<N2_BLOCKS, 256, 0, stream>>>(h2, SP0, gm, bt, flag, (float*)d_out);
}